// Round 1
// baseline (765.194 us; speedup 1.0000x reference)
//
#include <hip/hip_runtime.h>

typedef __bf16 bf16;
typedef __bf16 bf16x8 __attribute__((ext_vector_type(8)));
typedef float f32x4 __attribute__((ext_vector_type(4)));

#define AS1 __attribute__((address_space(1)))
#define AS3 __attribute__((address_space(3)))

__device__ __forceinline__ void gll16(const void* g, void* l) {
    __builtin_amdgcn_global_load_lds((const AS1 void*)g, (AS3 void*)l, 16, 0, 0);
}

// ---------------------------------------------------------------------------
// GEMM: C[m][n] = epi( sum_k A[m][k] * W[n][k] )   (A row-major [M][K] bf16,
// W packed [N][K] bf16). 128x128 tile, BK=64, 4 waves (2x2 of 64x64),
// mfma_f32_16x16x32_bf16. LDS XOR-swizzled (slot ^= row&7) for conflict-free
// ds_read_b128; staging via global_load_lds with pre-swizzled global source.
// EPI: 0 = plain bf16 store, 1 = bias+relu bf16, 2 = +dskip*U bf16,
//      3 = bias+softplus f32
// ---------------------------------------------------------------------------
template<int EPI>
__global__ __launch_bounds__(256)
void gemm_kern(const bf16* __restrict__ Abase, long long aBstride, int lda,
               const bf16* __restrict__ Wbase, long long wSstride,
               const float* __restrict__ biasBase, int biasStride,
               void* __restrict__ Cbase, long long cBstride, int ldc,
               const float* __restrict__ dskip,
               const bf16* __restrict__ Ubase, long long uBstride,
               const int* __restrict__ subj,
               int M, int K)
{
    __shared__ char smem[32768];
    char* ldsA = smem;
    char* ldsB = smem + 16384;

    const int tid = threadIdx.x;
    const int lane = tid & 63;
    const int wid = tid >> 6;
    const int wm = wid >> 1, wn = wid & 1;
    const int l15 = lane & 15, lhi = lane >> 4;

    const int b = blockIdx.z;
    const int s = subj ? subj[b] : 0;
    const bf16* A = Abase + (size_t)b * aBstride;
    const bf16* W = Wbase + (size_t)s * wSstride;
    const float* bias = biasBase ? biasBase + (size_t)s * biasStride : nullptr;
    const bf16* U = Ubase ? Ubase + (size_t)b * uBstride : nullptr;
    const size_t coff = (size_t)b * cBstride;

    const int n0 = blockIdx.x * 128;
    const int m0 = blockIdx.y * 128;

    f32x4 acc[4][4];
    #pragma unroll
    for (int i = 0; i < 4; ++i)
        #pragma unroll
        for (int j = 0; j < 4; ++j)
            acc[i][j] = f32x4{0.f, 0.f, 0.f, 0.f};

    int rbA[4], rbB[4];
    #pragma unroll
    for (int f = 0; f < 4; ++f) {
        rbA[f] = (wm*64 + f*16 + l15) * 128;
        rbB[f] = (wn*64 + f*16 + l15) * 128;
    }
    const int sw = l15 & 7;
    const int so = (wid << 10) + (lane << 4);

    const int nkt = K >> 6;
    for (int kt = 0; kt < nkt; ++kt) {
        #pragma unroll
        for (int r = 0; r < 4; ++r) {
            const int o = (r << 12) + so;
            const int row = o >> 7;
            const int slot = (o >> 4) & 7;
            const int gk = (kt << 6) + ((slot ^ (row & 7)) << 3);
            int ar = m0 + row; if (ar > M - 1) ar = M - 1;
            gll16(A + (size_t)ar * lda + gk, ldsA + (r << 12) + (wid << 10));
            gll16(W + (size_t)(n0 + row) * K + gk, ldsB + (r << 12) + (wid << 10));
        }
        __syncthreads();
        #pragma unroll
        for (int kk = 0; kk < 2; ++kk) {
            const int slot = (((kk << 2) | lhi) ^ sw) << 4;
            bf16x8 af[4], bfr[4];
            #pragma unroll
            for (int f = 0; f < 4; ++f) af[f]  = *(const bf16x8*)(ldsA + rbA[f] + slot);
            #pragma unroll
            for (int f = 0; f < 4; ++f) bfr[f] = *(const bf16x8*)(ldsB + rbB[f] + slot);
            #pragma unroll
            for (int i = 0; i < 4; ++i)
                #pragma unroll
                for (int j = 0; j < 4; ++j)
                    acc[i][j] = __builtin_amdgcn_mfma_f32_16x16x32_bf16(
                        af[i], bfr[j], acc[i][j], 0, 0, 0);
        }
        __syncthreads();
    }

    // epilogue: C/D layout col = lane&15, row = (lane>>4)*4 + reg  [m89-verified]
    #pragma unroll
    for (int i = 0; i < 4; ++i) {
        const int rb = m0 + wm*64 + i*16 + lhi*4;
        #pragma unroll
        for (int j = 0; j < 4; ++j) {
            const int col = n0 + wn*64 + j*16 + l15;
            f32x4 v = acc[i][j];
            #pragma unroll
            for (int q = 0; q < 4; ++q) {
                const int row = rb + q;
                if (row < M) {
                    float x = v[q];
                    const size_t ci = coff + (size_t)row * ldc + col;
                    if constexpr (EPI == 0) {
                        ((bf16*)Cbase)[ci] = (bf16)x;
                    } else if constexpr (EPI == 1) {
                        x += bias[col];
                        x = fmaxf(x, 0.f);
                        ((bf16*)Cbase)[ci] = (bf16)x;
                    } else if constexpr (EPI == 2) {
                        x += dskip[col] * (float)U[(size_t)row * ldc + col];
                        ((bf16*)Cbase)[ci] = (bf16)x;
                    } else {
                        x += bias[col];
                        x = fmaxf(x, 0.f) + log1pf(expf(-fabsf(x)));  // stable softplus
                        ((float*)Cbase)[ci] = x;
                    }
                }
            }
        }
    }
}

// ---------------------------------------------------------------------------
// Chunked LRU scan: T=1000 = 20 chunks x 50. Pass A: per-chunk local scan
// (x0=0), store finals. Pass B: sequential carry combine across chunks
// (P_c = L_c + lam^50 * P_{c-1}). Pass C: recompute local scan seeded with
// carry, emit xs (bf16, [t][re(0..255)|im(256..511)]).
// ---------------------------------------------------------------------------
__global__ void scan_finals(const bf16* __restrict__ Bu,
                            const float* __restrict__ nu_log,
                            const float* __restrict__ theta_log,
                            float2* __restrict__ finals)
{
    const int g = blockIdx.x * 256 + threadIdx.x;   // 32*20*256
    const int h = g & 255;
    const int c = (g >> 8) % 20;
    const int b = g / 5120;
    const float a  = expf(nu_log[h]);
    const float th = expf(theta_log[h]);
    const float mag = expf(-a);
    const float lre = mag * cosf(th), lim = mag * sinf(th);
    float xre = 0.f, xim = 0.f;
    const bf16* p = Bu + ((size_t)(b*1000 + c*50)) * 512 + h;
    for (int i = 0; i < 50; ++i) {
        const float bre = (float)p[0], bim = (float)p[256];
        const float nre = lre*xre - lim*xim + bre;
        const float nim = lre*xim + lim*xre + bim;
        xre = nre; xim = nim;
        p += 512;
    }
    finals[(b*20 + c)*256 + h] = make_float2(xre, xim);
}

__global__ void scan_carry(const float2* __restrict__ finals,
                           float2* __restrict__ carry,
                           const float* __restrict__ nu_log,
                           const float* __restrict__ theta_log)
{
    const int g = blockIdx.x * 256 + threadIdx.x;   // 32*256
    const int h = g & 255;
    const int b = g >> 8;
    const float a  = expf(nu_log[h]);
    const float th = expf(theta_log[h]);
    const float mag = expf(-50.f * a);
    const float ang = 50.f * th;
    const float cre = mag * cosf(ang), cim = mag * sinf(ang);
    float pre = 0.f, pim = 0.f;
    for (int c = 0; c < 20; ++c) {
        const int idx = (b*20 + c)*256 + h;
        carry[idx] = make_float2(pre, pim);
        const float2 f = finals[idx];
        const float nre = f.x + cre*pre - cim*pim;
        const float nim = f.y + cre*pim + cim*pre;
        pre = nre; pim = nim;
    }
}

__global__ void scan_emit(const bf16* __restrict__ Bu,
                          const float2* __restrict__ carry,
                          const float* __restrict__ nu_log,
                          const float* __restrict__ theta_log,
                          bf16* __restrict__ xs)
{
    const int g = blockIdx.x * 256 + threadIdx.x;
    const int h = g & 255;
    const int c = (g >> 8) % 20;
    const int b = g / 5120;
    const float a  = expf(nu_log[h]);
    const float th = expf(theta_log[h]);
    const float mag = expf(-a);
    const float lre = mag * cosf(th), lim = mag * sinf(th);
    const float2 cr = carry[(b*20 + c)*256 + h];
    float xre = cr.x, xim = cr.y;
    const bf16* p = Bu + ((size_t)(b*1000 + c*50)) * 512 + h;
    bf16* q = xs + ((size_t)(b*1000 + c*50)) * 512 + h;
    for (int i = 0; i < 50; ++i) {
        const float bre = (float)p[0], bim = (float)p[256];
        const float nre = lre*xre - lim*xim + bre;
        const float nim = lre*xim + lim*xre + bim;
        xre = nre; xim = nim;
        q[0] = (bf16)xre; q[256] = (bf16)xim;
        p += 512; q += 512;
    }
}

// ---------------------------------------------------------------------------
// small kernels
// ---------------------------------------------------------------------------
__global__ void cast8_kern(const float* __restrict__ src, bf16* __restrict__ dst, int n8)
{
    const int i = blockIdx.x * 256 + threadIdx.x;
    if (i >= n8) return;
    const float4* s = (const float4*)src + (size_t)i*2;
    const float4 v0 = s[0], v1 = s[1];
    bf16x8 o;
    o[0] = (bf16)v0.x; o[1] = (bf16)v0.y; o[2] = (bf16)v0.z; o[3] = (bf16)v0.w;
    o[4] = (bf16)v1.x; o[5] = (bf16)v1.y; o[6] = (bf16)v1.z; o[7] = (bf16)v1.w;
    *((bf16x8*)dst + i) = o;
}

// WB[l][n][k]: n<256 -> B_re[l][n][k]*g[l][n] ; n>=256 -> B_im[l][n-256][k]*g
__global__ void packWB_kern(const float* __restrict__ Bre, const float* __restrict__ Bim,
                            const float* __restrict__ glog, bf16* __restrict__ WB)
{
    const int idx = blockIdx.x * 256 + threadIdx.x;
    if (idx >= 4*512*768) return;
    const int l = idx / (512*768);
    const int r = idx - l*(512*768);
    const int n = r / 768;
    const int k = r - n*768;
    float v;
    if (n < 256) v = Bre[((size_t)(l*256 + n))*768 + k] * expf(glog[l*256 + n]);
    else         v = Bim[((size_t)(l*256 + (n-256)))*768 + k] * expf(glog[l*256 + (n-256)]);
    WB[idx] = (bf16)v;
}

// WC[l][o][k]: k<256 -> C_re[l][o][k] ; k>=256 -> -C_im[l][o][k-256]
__global__ void packWC_kern(const float* __restrict__ Cre, const float* __restrict__ Cim,
                            bf16* __restrict__ WC)
{
    const int idx = blockIdx.x * 256 + threadIdx.x;
    if (idx >= 4*768*512) return;
    const int l = idx / (768*512);
    const int r = idx - l*(768*512);
    const int o = r / 512;
    const int k = r - o*512;
    const float v = (k < 256) ? Cre[((size_t)(l*768 + o))*256 + k]
                              : -Cim[((size_t)(l*768 + o))*256 + (k - 256)];
    WC[idx] = (bf16)v;
}

__global__ void ctx_kern(const float* __restrict__ st, const int* __restrict__ sess,
                         const float* __restrict__ cW, const float* __restrict__ cb,
                         float* __restrict__ ctx)
{
    const int b = blockIdx.x;
    const int e = threadIdx.x;
    const int sid = sess[b];
    const float* r = st + (size_t)sid * 64;
    const float* w = cW + (size_t)e * 64;
    float acc = cb[e];
    #pragma unroll 8
    for (int i = 0; i < 64; ++i) acc += r[i] * w[i];
    ctx[b*256 + e] = fmaxf(acc, 0.f);
}

// per (b,t): behavior embed (K=16) -> h[256..511], ctx broadcast -> h[512..767]
__global__ void ebctx_kern(const float* __restrict__ behav,
                           const float* __restrict__ bW,
                           const float* __restrict__ bB,
                           const int* __restrict__ subj,
                           const float* __restrict__ ctx,
                           bf16* __restrict__ h0)
{
    const int blk = blockIdx.x;          // b*1000 + t
    const int b = blk / 1000;
    const int e = threadIdx.x;
    __shared__ float binp[16];
    if (e < 16) binp[e] = behav[(size_t)blk*16 + e];
    __syncthreads();
    const int s = subj[b];
    const float* w = bW + ((size_t)(s*256) + e)*16;
    float acc = bB[s*256 + e];
    #pragma unroll
    for (int i = 0; i < 16; ++i) acc += binp[i] * w[i];
    acc = fmaxf(acc, 0.f);
    bf16* hp = h0 + (size_t)blk * 768;
    hp[256 + e] = (bf16)acc;
    hp[512 + e] = (bf16)ctx[b*256 + e];
}

// pred_b: one wave per row, 2 outputs, K=768
__global__ void predb_kern(const bf16* __restrict__ h, const float* __restrict__ W,
                           const float* __restrict__ bb, const int* __restrict__ subj,
                           float* __restrict__ out)
{
    const int lane = threadIdx.x & 63;
    const int wid  = threadIdx.x >> 6;
    const int row  = blockIdx.x * 4 + wid;   // < 32000
    const int b = row / 1000;
    const int s = subj[b];
    const bf16* hr = h + (size_t)row * 768;
    const float* w0 = W + (size_t)(s*2) * 768;
    const float* w1 = w0 + 768;
    float a0 = 0.f, a1 = 0.f;
    #pragma unroll
    for (int j = 0; j < 12; ++j) {
        const int idx = j*64 + lane;
        const float hv = (float)hr[idx];
        a0 += hv * w0[idx];
        a1 += hv * w1[idx];
    }
    #pragma unroll
    for (int m = 32; m >= 1; m >>= 1) {
        a0 += __shfl_xor(a0, m);
        a1 += __shfl_xor(a1, m);
    }
    if (lane == 0) {
        out[(size_t)row*2 + 0] = a0 + bb[s*2 + 0];
        out[(size_t)row*2 + 1] = a1 + bb[s*2 + 1];
    }
}

// ---------------------------------------------------------------------------
extern "C" void kernel_launch(void* const* d_in, const int* in_sizes, int n_in,
                              void* d_out, int out_size, void* d_ws, size_t ws_size,
                              hipStream_t stream)
{
    const float* neural_input   = (const float*)d_in[0];
    const float* behavior_input = (const float*)d_in[1];
    const int*   session_id     = (const int*)d_in[2];
    const int*   subject_id     = (const int*)d_in[3];
    const float* session_table  = (const float*)d_in[4];
    const float* neural_W  = (const float*)d_in[5];
    const float* neural_b  = (const float*)d_in[6];
    const float* behavior_W = (const float*)d_in[7];
    const float* behavior_b = (const float*)d_in[8];
    const float* ctx_W = (const float*)d_in[9];
    const float* ctx_b = (const float*)d_in[10];
    const float* nu_log    = (const float*)d_in[11];
    const float* theta_log = (const float*)d_in[12];
    const float* gamma_log = (const float*)d_in[13];
    const float* B_re = (const float*)d_in[14];
    const float* B_im = (const float*)d_in[15];
    const float* C_re = (const float*)d_in[16];
    const float* C_im = (const float*)d_in[17];
    const float* D_skip = (const float*)d_in[18];
    const float* dec_n_W = (const float*)d_in[19];
    const float* dec_n_b = (const float*)d_in[20];
    const float* dec_b_W = (const float*)d_in[21];
    const float* dec_b_b = (const float*)d_in[22];
    float* out = (float*)d_out;

    char* ws = (char*)d_ws;
    size_t off = 0;
    auto alloc = [&](size_t bytes) -> char* {
        char* p = ws + off;
        off += (bytes + 255) & ~(size_t)255;
        return p;
    };
    bf16*   Wn      = (bf16*)alloc((size_t)8*256*512*2);    // 2 MB
    bf16*   Wd      = (bf16*)alloc((size_t)8*512*768*2);    // 6 MB
    bf16*   WB      = (bf16*)alloc((size_t)4*512*768*2);    // 3 MB
    bf16*   WC      = (bf16*)alloc((size_t)4*768*512*2);    // 3 MB
    float*  ctxbuf  = (float*)alloc((size_t)32*256*4);
    bf16*   hA      = (bf16*)alloc((size_t)32*1000*768*2);  // 49 MB
    bf16*   hB      = (bf16*)alloc((size_t)32*1000*768*2);  // 49 MB
    bf16*   xs      = (bf16*)alloc((size_t)32*1000*512*2);  // 33 MB
    float2* finals  = (float2*)alloc((size_t)32*20*256*8);
    float2* carry   = (float2*)alloc((size_t)32*20*256*8);
    bf16*   Bu      = (bf16*)alloc((size_t)32*1000*512*2);  // 33 MB
    bf16*   nbf     = Bu;  // alias: neural bf16 consumed before Bu is written

    // --- weight prep / casts ---
    cast8_kern<<<dim3(512),   256, 0, stream>>>(neural_W, Wn, 131072);
    cast8_kern<<<dim3(1536),  256, 0, stream>>>(dec_n_W,  Wd, 393216);
    packWB_kern<<<dim3(6144), 256, 0, stream>>>(B_re, B_im, gamma_log, WB);
    packWC_kern<<<dim3(6144), 256, 0, stream>>>(C_re, C_im, WC);
    ctx_kern<<<dim3(32), 256, 0, stream>>>(session_table, session_id, ctx_W, ctx_b, ctxbuf);
    cast8_kern<<<dim3(8000), 256, 0, stream>>>(neural_input, nbf, 2048000);

    // --- front end: h0 = [relu(en) | relu(eb) | relu(ctx)] ---
    ebctx_kern<<<dim3(32000), 256, 0, stream>>>(behavior_input, behavior_W, behavior_b,
                                                subject_id, ctxbuf, hA);
    gemm_kern<1><<<dim3(2, 8, 32), 256, 0, stream>>>(
        nbf, 512000LL, 512, Wn, 131072LL, neural_b, 256,
        hA, 768000LL, 768, nullptr, nullptr, 0LL, subject_id, 1000, 512);

    // --- 4 LRU layers ---
    for (int l = 0; l < 4; ++l) {
        const bf16* hin  = (l & 1) ? hB : hA;
        bf16*       hout = (l & 1) ? hA : hB;
        gemm_kern<0><<<dim3(4, 250, 1), 256, 0, stream>>>(
            hin, 0LL, 768, WB + (size_t)l*393216, 0LL, nullptr, 0,
            Bu, 0LL, 512, nullptr, nullptr, 0LL, nullptr, 32000, 768);
        scan_finals<<<dim3(640), 256, 0, stream>>>(Bu, nu_log + l*256, theta_log + l*256, finals);
        scan_carry<<<dim3(32), 256, 0, stream>>>(finals, carry, nu_log + l*256, theta_log + l*256);
        scan_emit<<<dim3(640), 256, 0, stream>>>(Bu, carry, nu_log + l*256, theta_log + l*256, xs);
        gemm_kern<2><<<dim3(6, 250, 1), 256, 0, stream>>>(
            xs, 0LL, 512, WC + (size_t)l*393216, 0LL, nullptr, 0,
            hout, 0LL, 768, D_skip + l*768, hin, 0LL, nullptr, 32000, 512);
    }

    // --- decoders (final h is hA after 4 layers) ---
    gemm_kern<3><<<dim3(4, 8, 32), 256, 0, stream>>>(
        hA, 768000LL, 768, Wd, 393216LL, dec_n_b, 512,
        out, 512000LL, 512, nullptr, nullptr, 0LL, subject_id, 1000, 768);
    predb_kern<<<dim3(8000), 256, 0, stream>>>(hA, dec_b_W, dec_b_b, subject_id,
                                               out + 16384000);
}

// Round 2
// 719.773 us; speedup vs baseline: 1.0631x; 1.0631x over previous
//
#include <hip/hip_runtime.h>

typedef __bf16 bf16;
typedef __bf16 bf16x8 __attribute__((ext_vector_type(8)));
typedef float f32x4 __attribute__((ext_vector_type(4)));

#define AS1 __attribute__((address_space(1)))
#define AS3 __attribute__((address_space(3)))

__device__ __forceinline__ void gll16(const void* g, void* l) {
    __builtin_amdgcn_global_load_lds((const AS1 void*)g, (AS3 void*)l, 16, 0, 0);
}

// ---------------------------------------------------------------------------
// GEMM: C[m][n] = epi( sum_k A[m][k] * W[n][k] )  (A [M][K] bf16 row-major,
// W [N][K] bf16). Tile 256x128, BK=64, 8 waves (4M x 2N), 512 threads.
// 3-buffer LDS pipeline (48 KB/buf = A 32K + B 16K), counted vmcnt(6),
// raw s_barrier once per K-tile, XOR-swizzled LDS (slot ^= row&7) for
// conflict-free ds_read_b128, setprio(1) around MFMA, bijective XCD swizzle.
// EPI: 0 = plain bf16 store, 1 = bias+relu bf16, 2 = +dskip*U bf16,
//      3 = bias+softplus f32
// ---------------------------------------------------------------------------
template<int EPI>
__global__ __launch_bounds__(512, 2)
void gemm_kern(const bf16* __restrict__ Abase, long long aBstride, int lda,
               const bf16* __restrict__ Wbase, long long wSstride,
               const float* __restrict__ biasBase, int biasStride,
               void* __restrict__ Cbase, long long cBstride, int ldc,
               const float* __restrict__ dskip,
               const bf16* __restrict__ Ubase, long long uBstride,
               const int* __restrict__ subj,
               int M, int K, int nbn)
{
    __shared__ char smem[147456];   // 3 x (A 32768 + B 16384)

    const int tid = threadIdx.x;
    const int lane = tid & 63;
    const int wid = tid >> 6;
    const int wm = wid >> 1, wn = wid & 1;       // 4 x 2 wave grid
    const int l15 = lane & 15, lhi = lane >> 4;
    const int sw7 = l15 & 7;

    // bijective XCD-aware block swizzle (m204) within this z-slice
    const int nwg = gridDim.x;
    const int bid = blockIdx.x;
    const int q = nwg >> 3, r = nwg & 7;
    const int xcd = bid & 7;
    const int sw = xcd * q + (xcd < r ? xcd : r) + (bid >> 3);
    const int m0 = (sw / nbn) * 256;
    const int n0 = (sw % nbn) * 128;

    const int b = blockIdx.z;
    const int s = subj ? subj[b] : 0;
    const bf16* A = Abase + (size_t)b * aBstride;
    const bf16* W = Wbase + (size_t)s * wSstride;
    const float* bias = biasBase ? biasBase + (size_t)s * biasStride : nullptr;
    const bf16* U = Ubase ? Ubase + (size_t)b * uBstride : nullptr;
    const size_t coff = (size_t)b * cBstride;
    const int Mc = M - 1;

    f32x4 acc[4][4];
    #pragma unroll
    for (int i = 0; i < 4; ++i)
        #pragma unroll
        for (int j = 0; j < 4; ++j)
            acc[i][j] = f32x4{0.f, 0.f, 0.f, 0.f};

    // LDS frag byte offsets (A region; B region adds 32768)
    int rA[4], rB[4];
    #pragma unroll
    for (int f = 0; f < 4; ++f) {
        rA[f] = (wm*64 + f*16 + l15) * 128;
        rB[f] = (wn*64 + f*16 + l15) * 128;
    }

    // staging geometry: per thread 6 x gll16 per K-tile
    const int sub  = tid >> 3;     // 0..63 -> row within 64-row chunk
    const int slot = tid & 7;      // 16B slot within 128B row
    const int ldsw = (wid << 10);  // wave-uniform LDS chunk base offset

    auto stage = [&](int kt, char* buf) {
        #pragma unroll
        for (int c = 0; c < 4; ++c) {           // A: 4 x 8KB chunks
            const int row = c*64 + sub;
            const int gk = (kt << 6) + ((slot ^ (row & 7)) << 3);
            int ar = m0 + row; if (ar > Mc) ar = Mc;
            gll16(A + (size_t)ar * lda + gk, buf + c*8192 + ldsw);
        }
        #pragma unroll
        for (int c = 0; c < 2; ++c) {           // B: 2 x 8KB chunks
            const int row = c*64 + sub;
            const int gk = (kt << 6) + ((slot ^ (row & 7)) << 3);
            gll16(W + (size_t)(n0 + row) * K + gk, buf + 32768 + c*8192 + ldsw);
        }
    };

    char* cur = smem;
    char* nxt = smem + 49152;
    char* nn  = smem + 98304;

    const int nkt = K >> 6;
    stage(0, cur);
    if (nkt > 1) stage(1, nxt);
    asm volatile("s_waitcnt vmcnt(6)" ::: "memory");
    __builtin_amdgcn_s_barrier();

    for (int t = 0; t < nkt; ++t) {
        if (t + 2 < nkt) stage(t + 2, nn);

        #pragma unroll
        for (int kk = 0; kk < 2; ++kk) {
            const int so_ = (((kk << 2) | lhi) ^ sw7) << 4;
            bf16x8 af[4], bg[4];
            #pragma unroll
            for (int f = 0; f < 4; ++f) af[f] = *(const bf16x8*)(cur + rA[f] + so_);
            #pragma unroll
            for (int g = 0; g < 4; ++g) bg[g] = *(const bf16x8*)(cur + 32768 + rB[g] + so_);
            __builtin_amdgcn_s_setprio(1);
            #pragma unroll
            for (int i = 0; i < 4; ++i)
                #pragma unroll
                for (int j = 0; j < 4; ++j)
                    acc[i][j] = __builtin_amdgcn_mfma_f32_16x16x32_bf16(
                        af[i], bg[j], acc[i][j], 0, 0, 0);
            __builtin_amdgcn_s_setprio(0);
        }

        if (t + 2 < nkt) {
            asm volatile("s_waitcnt vmcnt(6)" ::: "memory");   // tile t+1 landed
        } else if (t + 1 < nkt) {
            asm volatile("s_waitcnt vmcnt(0)" ::: "memory");   // tail drain
        }
        if (t + 1 < nkt) __builtin_amdgcn_s_barrier();

        char* tmp = cur; cur = nxt; nxt = nn; nn = tmp;
    }

    // epilogue: C/D layout col = lane&15, row = (lane>>4)*4 + reg
    #pragma unroll
    for (int i = 0; i < 4; ++i) {
        const int rb = m0 + wm*64 + i*16 + lhi*4;
        #pragma unroll
        for (int j = 0; j < 4; ++j) {
            const int col = n0 + wn*64 + j*16 + l15;
            f32x4 v = acc[i][j];
            #pragma unroll
            for (int qq = 0; qq < 4; ++qq) {
                const int row = rb + qq;
                if (row < M) {
                    float x = v[qq];
                    const size_t ci = coff + (size_t)row * ldc + col;
                    if constexpr (EPI == 0) {
                        ((bf16*)Cbase)[ci] = (bf16)x;
                    } else if constexpr (EPI == 1) {
                        x += bias[col];
                        x = fmaxf(x, 0.f);
                        ((bf16*)Cbase)[ci] = (bf16)x;
                    } else if constexpr (EPI == 2) {
                        x += dskip[col] * (float)U[(size_t)row * ldc + col];
                        ((bf16*)Cbase)[ci] = (bf16)x;
                    } else {
                        x += bias[col];
                        x = fmaxf(x, 0.f) + log1pf(expf(-fabsf(x)));  // stable softplus
                        ((float*)Cbase)[ci] = x;
                    }
                }
            }
        }
    }
}

// ---------------------------------------------------------------------------
// Chunked LRU scan: T=1000 = 20 chunks x 50. Pass A: per-chunk local scan
// (x0=0), store finals. Pass B: sequential carry combine across chunks.
// Pass C: recompute local scan seeded with carry, emit xs bf16.
// ---------------------------------------------------------------------------
__global__ void scan_finals(const bf16* __restrict__ Bu,
                            const float* __restrict__ nu_log,
                            const float* __restrict__ theta_log,
                            float2* __restrict__ finals)
{
    const int g = blockIdx.x * 256 + threadIdx.x;   // 32*20*256
    const int h = g & 255;
    const int c = (g >> 8) % 20;
    const int b = g / 5120;
    const float a  = expf(nu_log[h]);
    const float th = expf(theta_log[h]);
    const float mag = expf(-a);
    const float lre = mag * cosf(th), lim = mag * sinf(th);
    float xre = 0.f, xim = 0.f;
    const bf16* p = Bu + ((size_t)(b*1000 + c*50)) * 512 + h;
    for (int i = 0; i < 50; ++i) {
        const float bre = (float)p[0], bim = (float)p[256];
        const float nre = lre*xre - lim*xim + bre;
        const float nim = lre*xim + lim*xre + bim;
        xre = nre; xim = nim;
        p += 512;
    }
    finals[(b*20 + c)*256 + h] = make_float2(xre, xim);
}

__global__ void scan_carry(const float2* __restrict__ finals,
                           float2* __restrict__ carry,
                           const float* __restrict__ nu_log,
                           const float* __restrict__ theta_log)
{
    const int g = blockIdx.x * 256 + threadIdx.x;   // 32*256
    const int h = g & 255;
    const int b = g >> 8;
    const float a  = expf(nu_log[h]);
    const float th = expf(theta_log[h]);
    const float mag = expf(-50.f * a);
    const float ang = 50.f * th;
    const float cre = mag * cosf(ang), cim = mag * sinf(ang);
    float pre = 0.f, pim = 0.f;
    for (int c = 0; c < 20; ++c) {
        const int idx = (b*20 + c)*256 + h;
        carry[idx] = make_float2(pre, pim);
        const float2 f = finals[idx];
        const float nre = f.x + cre*pre - cim*pim;
        const float nim = f.y + cre*pim + cim*pre;
        pre = nre; pim = nim;
    }
}

__global__ void scan_emit(const bf16* __restrict__ Bu,
                          const float2* __restrict__ carry,
                          const float* __restrict__ nu_log,
                          const float* __restrict__ theta_log,
                          bf16* __restrict__ xs)
{
    const int g = blockIdx.x * 256 + threadIdx.x;
    const int h = g & 255;
    const int c = (g >> 8) % 20;
    const int b = g / 5120;
    const float a  = expf(nu_log[h]);
    const float th = expf(theta_log[h]);
    const float mag = expf(-a);
    const float lre = mag * cosf(th), lim = mag * sinf(th);
    const float2 cr = carry[(b*20 + c)*256 + h];
    float xre = cr.x, xim = cr.y;
    const bf16* p = Bu + ((size_t)(b*1000 + c*50)) * 512 + h;
    bf16* qp = xs + ((size_t)(b*1000 + c*50)) * 512 + h;
    for (int i = 0; i < 50; ++i) {
        const float bre = (float)p[0], bim = (float)p[256];
        const float nre = lre*xre - lim*xim + bre;
        const float nim = lre*xim + lim*xre + bim;
        xre = nre; xim = nim;
        qp[0] = (bf16)xre; qp[256] = (bf16)xim;
        p += 512; qp += 512;
    }
}

// ---------------------------------------------------------------------------
// small kernels
// ---------------------------------------------------------------------------
__global__ void cast8_kern(const float* __restrict__ src, bf16* __restrict__ dst, int n8)
{
    const int i = blockIdx.x * 256 + threadIdx.x;
    if (i >= n8) return;
    const float4* s = (const float4*)src + (size_t)i*2;
    const float4 v0 = s[0], v1 = s[1];
    bf16x8 o;
    o[0] = (bf16)v0.x; o[1] = (bf16)v0.y; o[2] = (bf16)v0.z; o[3] = (bf16)v0.w;
    o[4] = (bf16)v1.x; o[5] = (bf16)v1.y; o[6] = (bf16)v1.z; o[7] = (bf16)v1.w;
    *((bf16x8*)dst + i) = o;
}

__global__ void packWB_kern(const float* __restrict__ Bre, const float* __restrict__ Bim,
                            const float* __restrict__ glog, bf16* __restrict__ WB)
{
    const int idx = blockIdx.x * 256 + threadIdx.x;
    if (idx >= 4*512*768) return;
    const int l = idx / (512*768);
    const int r = idx - l*(512*768);
    const int n = r / 768;
    const int k = r - n*768;
    float v;
    if (n < 256) v = Bre[((size_t)(l*256 + n))*768 + k] * expf(glog[l*256 + n]);
    else         v = Bim[((size_t)(l*256 + (n-256)))*768 + k] * expf(glog[l*256 + (n-256)]);
    WB[idx] = (bf16)v;
}

__global__ void packWC_kern(const float* __restrict__ Cre, const float* __restrict__ Cim,
                            bf16* __restrict__ WC)
{
    const int idx = blockIdx.x * 256 + threadIdx.x;
    if (idx >= 4*768*512) return;
    const int l = idx / (768*512);
    const int r = idx - l*(768*512);
    const int o = r / 512;
    const int k = r - o*512;
    const float v = (k < 256) ? Cre[((size_t)(l*768 + o))*256 + k]
                              : -Cim[((size_t)(l*768 + o))*256 + (k - 256)];
    WC[idx] = (bf16)v;
}

__global__ void ctx_kern(const float* __restrict__ st, const int* __restrict__ sess,
                         const float* __restrict__ cW, const float* __restrict__ cb,
                         float* __restrict__ ctx)
{
    const int b = blockIdx.x;
    const int e = threadIdx.x;
    const int sid = sess[b];
    const float* r = st + (size_t)sid * 64;
    const float* w = cW + (size_t)e * 64;
    float acc = cb[e];
    #pragma unroll 8
    for (int i = 0; i < 64; ++i) acc += r[i] * w[i];
    ctx[b*256 + e] = fmaxf(acc, 0.f);
}

__global__ void ebctx_kern(const float* __restrict__ behav,
                           const float* __restrict__ bW,
                           const float* __restrict__ bB,
                           const int* __restrict__ subj,
                           const float* __restrict__ ctx,
                           bf16* __restrict__ h0)
{
    const int blk = blockIdx.x;          // b*1000 + t
    const int b = blk / 1000;
    const int e = threadIdx.x;
    __shared__ float binp[16];
    if (e < 16) binp[e] = behav[(size_t)blk*16 + e];
    __syncthreads();
    const int s = subj[b];
    const float* w = bW + ((size_t)(s*256) + e)*16;
    float acc = bB[s*256 + e];
    #pragma unroll
    for (int i = 0; i < 16; ++i) acc += binp[i] * w[i];
    acc = fmaxf(acc, 0.f);
    bf16* hp = h0 + (size_t)blk * 768;
    hp[256 + e] = (bf16)acc;
    hp[512 + e] = (bf16)ctx[b*256 + e];
}

__global__ void predb_kern(const bf16* __restrict__ h, const float* __restrict__ W,
                           const float* __restrict__ bb, const int* __restrict__ subj,
                           float* __restrict__ out)
{
    const int lane = threadIdx.x & 63;
    const int wid  = threadIdx.x >> 6;
    const int row  = blockIdx.x * 4 + wid;   // < 32000
    const int b = row / 1000;
    const int s = subj[b];
    const bf16* hr = h + (size_t)row * 768;
    const float* w0 = W + (size_t)(s*2) * 768;
    const float* w1 = w0 + 768;
    float a0 = 0.f, a1 = 0.f;
    #pragma unroll
    for (int j = 0; j < 12; ++j) {
        const int idx = j*64 + lane;
        const float hv = (float)hr[idx];
        a0 += hv * w0[idx];
        a1 += hv * w1[idx];
    }
    #pragma unroll
    for (int m = 32; m >= 1; m >>= 1) {
        a0 += __shfl_xor(a0, m);
        a1 += __shfl_xor(a1, m);
    }
    if (lane == 0) {
        out[(size_t)row*2 + 0] = a0 + bb[s*2 + 0];
        out[(size_t)row*2 + 1] = a1 + bb[s*2 + 1];
    }
}

// ---------------------------------------------------------------------------
extern "C" void kernel_launch(void* const* d_in, const int* in_sizes, int n_in,
                              void* d_out, int out_size, void* d_ws, size_t ws_size,
                              hipStream_t stream)
{
    const float* neural_input   = (const float*)d_in[0];
    const float* behavior_input = (const float*)d_in[1];
    const int*   session_id     = (const int*)d_in[2];
    const int*   subject_id     = (const int*)d_in[3];
    const float* session_table  = (const float*)d_in[4];
    const float* neural_W  = (const float*)d_in[5];
    const float* neural_b  = (const float*)d_in[6];
    const float* behavior_W = (const float*)d_in[7];
    const float* behavior_b = (const float*)d_in[8];
    const float* ctx_W = (const float*)d_in[9];
    const float* ctx_b = (const float*)d_in[10];
    const float* nu_log    = (const float*)d_in[11];
    const float* theta_log = (const float*)d_in[12];
    const float* gamma_log = (const float*)d_in[13];
    const float* B_re = (const float*)d_in[14];
    const float* B_im = (const float*)d_in[15];
    const float* C_re = (const float*)d_in[16];
    const float* C_im = (const float*)d_in[17];
    const float* D_skip = (const float*)d_in[18];
    const float* dec_n_W = (const float*)d_in[19];
    const float* dec_n_b = (const float*)d_in[20];
    const float* dec_b_W = (const float*)d_in[21];
    const float* dec_b_b = (const float*)d_in[22];
    float* out = (float*)d_out;

    char* ws = (char*)d_ws;
    size_t off = 0;
    auto alloc = [&](size_t bytes) -> char* {
        char* p = ws + off;
        off += (bytes + 255) & ~(size_t)255;
        return p;
    };
    bf16*   Wn      = (bf16*)alloc((size_t)8*256*512*2);
    bf16*   Wd      = (bf16*)alloc((size_t)8*512*768*2);
    bf16*   WB      = (bf16*)alloc((size_t)4*512*768*2);
    bf16*   WC      = (bf16*)alloc((size_t)4*768*512*2);
    float*  ctxbuf  = (float*)alloc((size_t)32*256*4);
    bf16*   hA      = (bf16*)alloc((size_t)32*1000*768*2);
    bf16*   hB      = (bf16*)alloc((size_t)32*1000*768*2);
    bf16*   xs      = (bf16*)alloc((size_t)32*1000*512*2);
    float2* finals  = (float2*)alloc((size_t)32*20*256*8);
    float2* carry   = (float2*)alloc((size_t)32*20*256*8);
    bf16*   Bu      = (bf16*)alloc((size_t)32*1000*512*2);
    bf16*   nbf     = Bu;  // alias: neural bf16 consumed before Bu is written

    // --- weight prep / casts ---
    cast8_kern<<<dim3(512),   256, 0, stream>>>(neural_W, Wn, 131072);
    cast8_kern<<<dim3(1536),  256, 0, stream>>>(dec_n_W,  Wd, 393216);
    packWB_kern<<<dim3(6144), 256, 0, stream>>>(B_re, B_im, gamma_log, WB);
    packWC_kern<<<dim3(6144), 256, 0, stream>>>(C_re, C_im, WC);
    ctx_kern<<<dim3(32), 256, 0, stream>>>(session_table, session_id, ctx_W, ctx_b, ctxbuf);
    cast8_kern<<<dim3(8000), 256, 0, stream>>>(neural_input, nbf, 2048000);

    // --- front end: h0 = [relu(en) | relu(eb) | relu(ctx)] ---
    ebctx_kern<<<dim3(32000), 256, 0, stream>>>(behavior_input, behavior_W, behavior_b,
                                                subject_id, ctxbuf, hA);
    // en: M=1000(z=32), N=256, K=512 -> nbm=4, nbn=2
    gemm_kern<1><<<dim3(8, 1, 32), 512, 0, stream>>>(
        nbf, 512000LL, 512, Wn, 131072LL, neural_b, 256,
        hA, 768000LL, 768, nullptr, nullptr, 0LL, subject_id, 1000, 512, 2);

    // --- 4 LRU layers ---
    for (int l = 0; l < 4; ++l) {
        const bf16* hin  = (l & 1) ? hB : hA;
        bf16*       hout = (l & 1) ? hA : hB;
        // Bu: M=32000, N=512, K=768 -> nbm=125, nbn=4
        gemm_kern<0><<<dim3(500, 1, 1), 512, 0, stream>>>(
            hin, 0LL, 768, WB + (size_t)l*393216, 0LL, nullptr, 0,
            Bu, 0LL, 512, nullptr, nullptr, 0LL, nullptr, 32000, 768, 4);
        scan_finals<<<dim3(640), 256, 0, stream>>>(Bu, nu_log + l*256, theta_log + l*256, finals);
        scan_carry<<<dim3(32), 256, 0, stream>>>(finals, carry, nu_log + l*256, theta_log + l*256);
        scan_emit<<<dim3(640), 256, 0, stream>>>(Bu, carry, nu_log + l*256, theta_log + l*256, xs);
        // y: M=32000, N=768, K=512 -> nbm=125, nbn=6
        gemm_kern<2><<<dim3(750, 1, 1), 512, 0, stream>>>(
            xs, 0LL, 512, WC + (size_t)l*393216, 0LL, nullptr, 0,
            hout, 0LL, 768, D_skip + l*768, hin, 0LL, nullptr, 32000, 512, 6);
    }

    // --- decoders (final h is hA after 4 layers) ---
    // dec_n: M=1000(z=32), N=512, K=768 -> nbm=4, nbn=4
    gemm_kern<3><<<dim3(16, 1, 32), 512, 0, stream>>>(
        hA, 768000LL, 768, Wd, 393216LL, dec_n_b, 512,
        out, 512000LL, 512, nullptr, nullptr, 0LL, subject_id, 1000, 768, 4);
    predb_kern<<<dim3(8000), 256, 0, stream>>>(hA, dec_b_W, dec_b_b, subject_id,
                                               out + 16384000);
}

// Round 3
// 606.354 us; speedup vs baseline: 1.2620x; 1.1871x over previous
//
#include <hip/hip_runtime.h>

typedef __bf16 bf16;
typedef __bf16 bf16x8 __attribute__((ext_vector_type(8)));
typedef float f32x4 __attribute__((ext_vector_type(4)));

#define AS1 __attribute__((address_space(1)))
#define AS3 __attribute__((address_space(3)))

__device__ __forceinline__ void gll16(const void* g, void* l) {
    __builtin_amdgcn_global_load_lds((const AS1 void*)g, (AS3 void*)l, 16, 0, 0);
}

// ---------------------------------------------------------------------------
// GEMM: C[m][n] = epi( sum_k A[m][k] * W[n][k] )  (A [M][K] bf16 row-major,
// W [N][K] bf16). Tile 256x128, BK=64, 8 waves (4M x 2N), 512 threads.
// 3-buffer LDS pipeline, counted vmcnt(6), raw s_barrier per K-tile,
// XOR-swizzled LDS for conflict-free ds_read_b128, bijective XCD swizzle.
// Epilogue: acc -> swizzled bf16 LDS image -> contiguous bf16x8 stores
// (full-sector writes; U/bias/dskip loaded as vectors at read side).
// EPI: 0 = plain bf16 store, 1 = bias+relu bf16, 2 = +dskip*U bf16,
//      3 = bias+softplus f32
// ---------------------------------------------------------------------------
template<int EPI>
__global__ __launch_bounds__(512, 2)
void gemm_kern(const bf16* __restrict__ Abase, long long aBstride, int lda,
               const bf16* __restrict__ Wbase, long long wSstride,
               const float* __restrict__ biasBase, int biasStride,
               void* __restrict__ Cbase, long long cBstride, int ldc,
               const float* __restrict__ dskip,
               const bf16* __restrict__ Ubase, long long uBstride,
               const int* __restrict__ subj,
               int M, int K, int nbn)
{
    __shared__ char smem[147456];   // 3 x (A 32768 + B 16384); epilogue reuses 64 KB

    const int tid = threadIdx.x;
    const int lane = tid & 63;
    const int wid = tid >> 6;
    const int wm = wid >> 1, wn = wid & 1;       // 4 x 2 wave grid
    const int l15 = lane & 15, lhi = lane >> 4;
    const int sw7 = l15 & 7;

    // bijective XCD-aware block swizzle (m204)
    const int nwg = gridDim.x;
    const int bid = blockIdx.x;
    const int q = nwg >> 3, r = nwg & 7;
    const int xcd = bid & 7;
    const int sw = xcd * q + (xcd < r ? xcd : r) + (bid >> 3);
    const int m0 = (sw / nbn) * 256;
    const int n0 = (sw % nbn) * 128;

    const int b = blockIdx.z;
    const int s = subj ? subj[b] : 0;
    const bf16* A = Abase + (size_t)b * aBstride;
    const bf16* W = Wbase + (size_t)s * wSstride;
    const float* bias = biasBase ? biasBase + (size_t)s * biasStride : nullptr;
    const bf16* U = Ubase ? Ubase + (size_t)b * uBstride : nullptr;
    const size_t coff = (size_t)b * cBstride;
    const int Mc = M - 1;

    f32x4 acc[4][4];
    #pragma unroll
    for (int i = 0; i < 4; ++i)
        #pragma unroll
        for (int j = 0; j < 4; ++j)
            acc[i][j] = f32x4{0.f, 0.f, 0.f, 0.f};

    int rA[4], rB[4];
    #pragma unroll
    for (int f = 0; f < 4; ++f) {
        rA[f] = (wm*64 + f*16 + l15) * 128;
        rB[f] = (wn*64 + f*16 + l15) * 128;
    }

    const int sub  = tid >> 3;     // 0..63 row within 64-row chunk
    const int slot = tid & 7;      // 16B slot within 128B row
    const int ldsw = (wid << 10);  // wave-uniform LDS chunk base offset

    auto stage = [&](int kt, char* buf) {
        #pragma unroll
        for (int c = 0; c < 4; ++c) {           // A: 4 x 8KB chunks
            const int row = c*64 + sub;
            const int gk = (kt << 6) + ((slot ^ (row & 7)) << 3);
            int ar = m0 + row; if (ar > Mc) ar = Mc;
            gll16(A + (size_t)ar * lda + gk, buf + c*8192 + ldsw);
        }
        #pragma unroll
        for (int c = 0; c < 2; ++c) {           // B: 2 x 8KB chunks
            const int row = c*64 + sub;
            const int gk = (kt << 6) + ((slot ^ (row & 7)) << 3);
            gll16(W + (size_t)(n0 + row) * K + gk, buf + 32768 + c*8192 + ldsw);
        }
    };

    char* cur = smem;
    char* nxt = smem + 49152;
    char* nn  = smem + 98304;

    const int nkt = K >> 6;
    stage(0, cur);
    if (nkt > 1) stage(1, nxt);
    asm volatile("s_waitcnt vmcnt(6)" ::: "memory");
    __builtin_amdgcn_s_barrier();

    for (int t = 0; t < nkt; ++t) {
        if (t + 2 < nkt) stage(t + 2, nn);

        #pragma unroll
        for (int kk = 0; kk < 2; ++kk) {
            const int so_ = (((kk << 2) | lhi) ^ sw7) << 4;
            bf16x8 af[4], bg[4];
            #pragma unroll
            for (int f = 0; f < 4; ++f) af[f] = *(const bf16x8*)(cur + rA[f] + so_);
            #pragma unroll
            for (int g = 0; g < 4; ++g) bg[g] = *(const bf16x8*)(cur + 32768 + rB[g] + so_);
            #pragma unroll
            for (int i = 0; i < 4; ++i)
                #pragma unroll
                for (int j = 0; j < 4; ++j)
                    acc[i][j] = __builtin_amdgcn_mfma_f32_16x16x32_bf16(
                        af[i], bg[j], acc[i][j], 0, 0, 0);
        }

        if (t + 2 < nkt) {
            asm volatile("s_waitcnt vmcnt(6)" ::: "memory");   // tile t+1 landed
        } else if (t + 1 < nkt) {
            asm volatile("s_waitcnt vmcnt(0)" ::: "memory");   // tail drain
        }
        if (t + 1 < nkt) __builtin_amdgcn_s_barrier();

        char* tmp = cur; cur = nxt; nxt = nn; nn = tmp;
    }

    // ---- epilogue: acc -> swizzled bf16 LDS image [256][128] -> vector IO ----
    __syncthreads();
    #pragma unroll
    for (int i = 0; i < 4; ++i) {
        #pragma unroll
        for (int j = 0; j < 4; ++j) {
            const int colb = (wn*64 + j*16 + l15) * 2;
            const f32x4 v = acc[i][j];
            #pragma unroll
            for (int qq = 0; qq < 4; ++qq) {
                const int row = wm*64 + i*16 + lhi*4 + qq;
                const int ad = row*256 + (colb & 15) + ((((colb >> 4) ^ (row & 7)) & 15) << 4);
                *(bf16*)(smem + ad) = (bf16)v[qq];
            }
        }
    }
    __syncthreads();

    #pragma unroll
    for (int u = 0; u < 8; ++u) {
        const int chunk = u*512 + tid;
        const int rr = chunk >> 4, ss = chunk & 15;
        const int gr = m0 + rr;
        if (gr >= M) continue;
        const int col = n0 + ss*8;
        const bf16x8 v = *(const bf16x8*)(smem + rr*256 + ((ss ^ (rr & 7)) << 4));
        if constexpr (EPI == 0) {
            const size_t ci = coff + (size_t)gr * ldc + col;
            *(bf16x8*)((bf16*)Cbase + ci) = v;
        } else if constexpr (EPI == 1) {
            const float4 b0 = *(const float4*)(bias + col);
            const float4 b1 = *(const float4*)(bias + col + 4);
            bf16x8 o;
            o[0] = (bf16)fmaxf((float)v[0] + b0.x, 0.f);
            o[1] = (bf16)fmaxf((float)v[1] + b0.y, 0.f);
            o[2] = (bf16)fmaxf((float)v[2] + b0.z, 0.f);
            o[3] = (bf16)fmaxf((float)v[3] + b0.w, 0.f);
            o[4] = (bf16)fmaxf((float)v[4] + b1.x, 0.f);
            o[5] = (bf16)fmaxf((float)v[5] + b1.y, 0.f);
            o[6] = (bf16)fmaxf((float)v[6] + b1.z, 0.f);
            o[7] = (bf16)fmaxf((float)v[7] + b1.w, 0.f);
            const size_t ci = coff + (size_t)gr * ldc + col;
            *(bf16x8*)((bf16*)Cbase + ci) = o;
        } else if constexpr (EPI == 2) {
            const bf16x8 uv = *(const bf16x8*)(U + (size_t)gr * ldc + col);
            const float4 d0 = *(const float4*)(dskip + col);
            const float4 d1 = *(const float4*)(dskip + col + 4);
            bf16x8 o;
            o[0] = (bf16)((float)v[0] + d0.x * (float)uv[0]);
            o[1] = (bf16)((float)v[1] + d0.y * (float)uv[1]);
            o[2] = (bf16)((float)v[2] + d0.z * (float)uv[2]);
            o[3] = (bf16)((float)v[3] + d0.w * (float)uv[3]);
            o[4] = (bf16)((float)v[4] + d1.x * (float)uv[4]);
            o[5] = (bf16)((float)v[5] + d1.y * (float)uv[5]);
            o[6] = (bf16)((float)v[6] + d1.z * (float)uv[6]);
            o[7] = (bf16)((float)v[7] + d1.w * (float)uv[7]);
            const size_t ci = coff + (size_t)gr * ldc + col;
            *(bf16x8*)((bf16*)Cbase + ci) = o;
        } else {
            const float4 b0 = *(const float4*)(bias + col);
            const float4 b1 = *(const float4*)(bias + col + 4);
            float xv[8];
            xv[0] = (float)v[0] + b0.x; xv[1] = (float)v[1] + b0.y;
            xv[2] = (float)v[2] + b0.z; xv[3] = (float)v[3] + b0.w;
            xv[4] = (float)v[4] + b1.x; xv[5] = (float)v[5] + b1.y;
            xv[6] = (float)v[6] + b1.z; xv[7] = (float)v[7] + b1.w;
            float4 o0, o1;
            #pragma unroll
            for (int e = 0; e < 8; ++e) {
                const float x = xv[e];
                const float sp = fmaxf(x, 0.f) + log1pf(expf(-fabsf(x)));
                if (e < 4) ((float*)&o0)[e] = sp; else ((float*)&o1)[e-4] = sp;
            }
            const size_t ci = coff + (size_t)gr * ldc + col;
            *(float4*)((float*)Cbase + ci) = o0;
            *(float4*)((float*)Cbase + ci + 4) = o1;
        }
    }
}

// ---------------------------------------------------------------------------
// Chunked LRU scan: T=1000 = 20 chunks x 50.
// ---------------------------------------------------------------------------
__global__ void scan_finals(const bf16* __restrict__ Bu,
                            const float* __restrict__ nu_log,
                            const float* __restrict__ theta_log,
                            float2* __restrict__ finals)
{
    const int g = blockIdx.x * 256 + threadIdx.x;   // 32*20*256
    const int h = g & 255;
    const int c = (g >> 8) % 20;
    const int b = g / 5120;
    const float a  = expf(nu_log[h]);
    const float th = expf(theta_log[h]);
    const float mag = expf(-a);
    const float lre = mag * cosf(th), lim = mag * sinf(th);
    float xre = 0.f, xim = 0.f;
    const bf16* p = Bu + ((size_t)(b*1000 + c*50)) * 512 + h;
    for (int i = 0; i < 50; ++i) {
        const float bre = (float)p[0], bim = (float)p[256];
        const float nre = lre*xre - lim*xim + bre;
        const float nim = lre*xim + lim*xre + bim;
        xre = nre; xim = nim;
        p += 512;
    }
    finals[(b*20 + c)*256 + h] = make_float2(xre, xim);
}

__global__ void scan_carry(const float2* __restrict__ finals,
                           float2* __restrict__ carry,
                           const float* __restrict__ nu_log,
                           const float* __restrict__ theta_log)
{
    const int g = blockIdx.x * 256 + threadIdx.x;   // 32*256
    const int h = g & 255;
    const int b = g >> 8;
    const float a  = expf(nu_log[h]);
    const float th = expf(theta_log[h]);
    const float mag = expf(-50.f * a);
    const float ang = 50.f * th;
    const float cre = mag * cosf(ang), cim = mag * sinf(ang);
    float pre = 0.f, pim = 0.f;
    for (int c = 0; c < 20; ++c) {
        const int idx = (b*20 + c)*256 + h;
        carry[idx] = make_float2(pre, pim);
        const float2 f = finals[idx];
        const float nre = f.x + cre*pre - cim*pim;
        const float nim = f.y + cre*pim + cim*pre;
        pre = nre; pim = nim;
    }
}

__global__ void scan_emit(const bf16* __restrict__ Bu,
                          const float2* __restrict__ carry,
                          const float* __restrict__ nu_log,
                          const float* __restrict__ theta_log,
                          bf16* __restrict__ xs)
{
    const int g = blockIdx.x * 256 + threadIdx.x;
    const int h = g & 255;
    const int c = (g >> 8) % 20;
    const int b = g / 5120;
    const float a  = expf(nu_log[h]);
    const float th = expf(theta_log[h]);
    const float mag = expf(-a);
    const float lre = mag * cosf(th), lim = mag * sinf(th);
    const float2 cr = carry[(b*20 + c)*256 + h];
    float xre = cr.x, xim = cr.y;
    const bf16* p = Bu + ((size_t)(b*1000 + c*50)) * 512 + h;
    bf16* qp = xs + ((size_t)(b*1000 + c*50)) * 512 + h;
    for (int i = 0; i < 50; ++i) {
        const float bre = (float)p[0], bim = (float)p[256];
        const float nre = lre*xre - lim*xim + bre;
        const float nim = lre*xim + lim*xre + bim;
        xre = nre; xim = nim;
        qp[0] = (bf16)xre; qp[256] = (bf16)xim;
        p += 512; qp += 512;
    }
}

// ---------------------------------------------------------------------------
// small kernels
// ---------------------------------------------------------------------------
__global__ void cast8_kern(const float* __restrict__ src, bf16* __restrict__ dst, int n8)
{
    const int i = blockIdx.x * 256 + threadIdx.x;
    if (i >= n8) return;
    const float4* s = (const float4*)src + (size_t)i*2;
    const float4 v0 = s[0], v1 = s[1];
    bf16x8 o;
    o[0] = (bf16)v0.x; o[1] = (bf16)v0.y; o[2] = (bf16)v0.z; o[3] = (bf16)v0.w;
    o[4] = (bf16)v1.x; o[5] = (bf16)v1.y; o[6] = (bf16)v1.z; o[7] = (bf16)v1.w;
    *((bf16x8*)dst + i) = o;
}

__global__ void packWB_kern(const float* __restrict__ Bre, const float* __restrict__ Bim,
                            const float* __restrict__ glog, bf16* __restrict__ WB)
{
    const int idx = blockIdx.x * 256 + threadIdx.x;
    if (idx >= 4*512*768) return;
    const int l = idx / (512*768);
    const int r = idx - l*(512*768);
    const int n = r / 768;
    const int k = r - n*768;
    float v;
    if (n < 256) v = Bre[((size_t)(l*256 + n))*768 + k] * expf(glog[l*256 + n]);
    else         v = Bim[((size_t)(l*256 + (n-256)))*768 + k] * expf(glog[l*256 + (n-256)]);
    WB[idx] = (bf16)v;
}

__global__ void packWC_kern(const float* __restrict__ Cre, const float* __restrict__ Cim,
                            bf16* __restrict__ WC)
{
    const int idx = blockIdx.x * 256 + threadIdx.x;
    if (idx >= 4*768*512) return;
    const int l = idx / (768*512);
    const int r = idx - l*(768*512);
    const int o = r / 512;
    const int k = r - o*512;
    const float v = (k < 256) ? Cre[((size_t)(l*768 + o))*256 + k]
                              : -Cim[((size_t)(l*768 + o))*256 + (k - 256)];
    WC[idx] = (bf16)v;
}

__global__ void ctx_kern(const float* __restrict__ st, const int* __restrict__ sess,
                         const float* __restrict__ cW, const float* __restrict__ cb,
                         float* __restrict__ ctx)
{
    const int b = blockIdx.x;
    const int e = threadIdx.x;
    const int sid = sess[b];
    const float* r = st + (size_t)sid * 64;
    const float* w = cW + (size_t)e * 64;
    float acc = cb[e];
    #pragma unroll 8
    for (int i = 0; i < 64; ++i) acc += r[i] * w[i];
    ctx[b*256 + e] = fmaxf(acc, 0.f);
}

__global__ void ebctx_kern(const float* __restrict__ behav,
                           const float* __restrict__ bW,
                           const float* __restrict__ bB,
                           const int* __restrict__ subj,
                           const float* __restrict__ ctx,
                           bf16* __restrict__ h0)
{
    const int blk = blockIdx.x;          // b*1000 + t
    const int b = blk / 1000;
    const int e = threadIdx.x;
    __shared__ float binp[16];
    if (e < 16) binp[e] = behav[(size_t)blk*16 + e];
    __syncthreads();
    const int s = subj[b];
    const float* w = bW + ((size_t)(s*256) + e)*16;
    float acc = bB[s*256 + e];
    #pragma unroll
    for (int i = 0; i < 16; ++i) acc += binp[i] * w[i];
    acc = fmaxf(acc, 0.f);
    bf16* hp = h0 + (size_t)blk * 768;
    hp[256 + e] = (bf16)acc;
    hp[512 + e] = (bf16)ctx[b*256 + e];
}

__global__ void predb_kern(const bf16* __restrict__ h, const float* __restrict__ W,
                           const float* __restrict__ bb, const int* __restrict__ subj,
                           float* __restrict__ out)
{
    const int lane = threadIdx.x & 63;
    const int wid  = threadIdx.x >> 6;
    const int row  = blockIdx.x * 4 + wid;   // < 32000
    const int b = row / 1000;
    const int s = subj[b];
    const bf16* hr = h + (size_t)row * 768;
    const float* w0 = W + (size_t)(s*2) * 768;
    const float* w1 = w0 + 768;
    float a0 = 0.f, a1 = 0.f;
    #pragma unroll
    for (int j = 0; j < 12; ++j) {
        const int idx = j*64 + lane;
        const float hv = (float)hr[idx];
        a0 += hv * w0[idx];
        a1 += hv * w1[idx];
    }
    #pragma unroll
    for (int m = 32; m >= 1; m >>= 1) {
        a0 += __shfl_xor(a0, m);
        a1 += __shfl_xor(a1, m);
    }
    if (lane == 0) {
        out[(size_t)row*2 + 0] = a0 + bb[s*2 + 0];
        out[(size_t)row*2 + 1] = a1 + bb[s*2 + 1];
    }
}

// ---------------------------------------------------------------------------
extern "C" void kernel_launch(void* const* d_in, const int* in_sizes, int n_in,
                              void* d_out, int out_size, void* d_ws, size_t ws_size,
                              hipStream_t stream)
{
    const float* neural_input   = (const float*)d_in[0];
    const float* behavior_input = (const float*)d_in[1];
    const int*   session_id     = (const int*)d_in[2];
    const int*   subject_id     = (const int*)d_in[3];
    const float* session_table  = (const float*)d_in[4];
    const float* neural_W  = (const float*)d_in[5];
    const float* neural_b  = (const float*)d_in[6];
    const float* behavior_W = (const float*)d_in[7];
    const float* behavior_b = (const float*)d_in[8];
    const float* ctx_W = (const float*)d_in[9];
    const float* ctx_b = (const float*)d_in[10];
    const float* nu_log    = (const float*)d_in[11];
    const float* theta_log = (const float*)d_in[12];
    const float* gamma_log = (const float*)d_in[13];
    const float* B_re = (const float*)d_in[14];
    const float* B_im = (const float*)d_in[15];
    const float* C_re = (const float*)d_in[16];
    const float* C_im = (const float*)d_in[17];
    const float* D_skip = (const float*)d_in[18];
    const float* dec_n_W = (const float*)d_in[19];
    const float* dec_n_b = (const float*)d_in[20];
    const float* dec_b_W = (const float*)d_in[21];
    const float* dec_b_b = (const float*)d_in[22];
    float* out = (float*)d_out;

    char* ws = (char*)d_ws;
    size_t off = 0;
    auto alloc = [&](size_t bytes) -> char* {
        char* p = ws + off;
        off += (bytes + 255) & ~(size_t)255;
        return p;
    };
    bf16*   Wn      = (bf16*)alloc((size_t)8*256*512*2);
    bf16*   Wd      = (bf16*)alloc((size_t)8*512*768*2);
    bf16*   WB      = (bf16*)alloc((size_t)4*512*768*2);
    bf16*   WC      = (bf16*)alloc((size_t)4*768*512*2);
    float*  ctxbuf  = (float*)alloc((size_t)32*256*4);
    bf16*   hA      = (bf16*)alloc((size_t)32*1000*768*2);
    bf16*   hB      = (bf16*)alloc((size_t)32*1000*768*2);
    bf16*   xs      = (bf16*)alloc((size_t)32*1000*512*2);
    float2* finals  = (float2*)alloc((size_t)32*20*256*8);
    float2* carry   = (float2*)alloc((size_t)32*20*256*8);
    bf16*   Bu      = (bf16*)alloc((size_t)32*1000*512*2);
    bf16*   nbf     = Bu;  // alias: neural bf16 consumed before Bu is written

    // --- weight prep / casts ---
    cast8_kern<<<dim3(512),   256, 0, stream>>>(neural_W, Wn, 131072);
    cast8_kern<<<dim3(1536),  256, 0, stream>>>(dec_n_W,  Wd, 393216);
    packWB_kern<<<dim3(6144), 256, 0, stream>>>(B_re, B_im, gamma_log, WB);
    packWC_kern<<<dim3(6144), 256, 0, stream>>>(C_re, C_im, WC);
    ctx_kern<<<dim3(32), 256, 0, stream>>>(session_table, session_id, ctx_W, ctx_b, ctxbuf);
    cast8_kern<<<dim3(8000), 256, 0, stream>>>(neural_input, nbf, 2048000);

    // --- front end: h0 = [relu(en) | relu(eb) | relu(ctx)] ---
    ebctx_kern<<<dim3(32000), 256, 0, stream>>>(behavior_input, behavior_W, behavior_b,
                                                subject_id, ctxbuf, hA);
    // en: M=1000(z=32), N=256, K=512 -> nbm=4, nbn=2
    gemm_kern<1><<<dim3(8, 1, 32), 512, 0, stream>>>(
        nbf, 512000LL, 512, Wn, 131072LL, neural_b, 256,
        hA, 768000LL, 768, nullptr, nullptr, 0LL, subject_id, 1000, 512, 2);

    // --- 4 LRU layers ---
    for (int l = 0; l < 4; ++l) {
        const bf16* hin  = (l & 1) ? hB : hA;
        bf16*       hout = (l & 1) ? hA : hB;
        // Bu: M=32000, N=512, K=768 -> nbm=125, nbn=4
        gemm_kern<0><<<dim3(500, 1, 1), 512, 0, stream>>>(
            hin, 0LL, 768, WB + (size_t)l*393216, 0LL, nullptr, 0,
            Bu, 0LL, 512, nullptr, nullptr, 0LL, nullptr, 32000, 768, 4);
        scan_finals<<<dim3(640), 256, 0, stream>>>(Bu, nu_log + l*256, theta_log + l*256, finals);
        scan_carry<<<dim3(32), 256, 0, stream>>>(finals, carry, nu_log + l*256, theta_log + l*256);
        scan_emit<<<dim3(640), 256, 0, stream>>>(Bu, carry, nu_log + l*256, theta_log + l*256, xs);
        // y: M=32000, N=768, K=512 -> nbm=125, nbn=6
        gemm_kern<2><<<dim3(750, 1, 1), 512, 0, stream>>>(
            xs, 0LL, 512, WC + (size_t)l*393216, 0LL, nullptr, 0,
            hout, 0LL, 768, D_skip + l*768, hin, 0LL, nullptr, 32000, 512, 6);
    }

    // --- decoders (final h is hA after 4 layers) ---
    // dec_n: M=1000(z=32), N=512, K=768 -> nbm=4, nbn=4
    gemm_kern<3><<<dim3(16, 1, 32), 512, 0, stream>>>(
        hA, 768000LL, 768, Wd, 393216LL, dec_n_b, 512,
        out, 512000LL, 512, nullptr, nullptr, 0LL, subject_id, 1000, 768, 4);
    predb_kern<<<dim3(8000), 256, 0, stream>>>(hA, dec_b_W, dec_b_b, subject_id,
                                               out + 16384000);
}

// Round 5
// 598.914 us; speedup vs baseline: 1.2776x; 1.0124x over previous
//
#include <hip/hip_runtime.h>

typedef __bf16 bf16;
typedef __bf16 bf16x8 __attribute__((ext_vector_type(8)));
typedef float f32x4 __attribute__((ext_vector_type(4)));

#define AS1 __attribute__((address_space(1)))
#define AS3 __attribute__((address_space(3)))

__device__ __forceinline__ void gll16(const void* g, void* l) {
    __builtin_amdgcn_global_load_lds((const AS1 void*)g, (AS3 void*)l, 16, 0, 0);
}

// ---------------------------------------------------------------------------
// GEMM: C[m][n] = epi( sum_k A[m][k] * W[n][k] )  (A [M][K] bf16 row-major,
// W [N][K] bf16). Tile 128x128, BK=32, 4 waves (2x2 of 64x64), 256 threads.
// 3-buffer LDS pipeline (16 KB/buf: A 8K + B 8K) = 48 KB -> 3 blocks/CU of
// independent barrier domains (latency hiding across blocks). Counted
// vmcnt(4), one s_barrier per K-step, XOR-swizzled LDS (slot ^= row&3,
// 64 B rows) for conflict-free ds_read_b128, bijective XCD swizzle.
// Epilogue: acc -> swizzled bf16 LDS image [128][128] -> vector stores.
// EPI: 0 = plain bf16, 1 = bias+relu bf16, 2 = +dskip*U bf16,
//      3 = bias+softplus f32
// ---------------------------------------------------------------------------
template<int EPI>
__global__ __launch_bounds__(256, 3)
void gemm_kern(const bf16* __restrict__ Abase, long long aBstride, int lda,
               const bf16* __restrict__ Wbase, long long wSstride,
               const float* __restrict__ biasBase, int biasStride,
               void* __restrict__ Cbase, long long cBstride, int ldc,
               const float* __restrict__ dskip,
               const bf16* __restrict__ Ubase, long long uBstride,
               const int* __restrict__ subj,
               int M, int K, int nbn)
{
    __shared__ char smem[49152];   // 3 x (A 8192 + B 8192); epilogue image 32 KB

    const int tid = threadIdx.x;
    const int lane = tid & 63;
    const int wid = tid >> 6;
    const int wm = wid >> 1, wn = wid & 1;       // 2 x 2 wave grid, 64x64 each
    const int l15 = lane & 15, lhi = lane >> 4;
    const int sw3 = l15 & 3;

    // bijective XCD-aware block swizzle (m204)
    const int nwg = gridDim.x;
    const int bid = blockIdx.x;
    const int q = nwg >> 3, r = nwg & 7;
    const int xcd = bid & 7;
    const int sw = xcd * q + (xcd < r ? xcd : r) + (bid >> 3);
    const int m0 = (sw / nbn) * 128;
    const int n0 = (sw % nbn) * 128;

    const int b = blockIdx.z;
    const int s = subj ? subj[b] : 0;
    const bf16* A = Abase + (size_t)b * aBstride;
    const bf16* W = Wbase + (size_t)s * wSstride;
    const float* bias = biasBase ? biasBase + (size_t)s * biasStride : nullptr;
    const bf16* U = Ubase ? Ubase + (size_t)b * uBstride : nullptr;
    const size_t coff = (size_t)b * cBstride;
    const int Mc = M - 1;

    f32x4 acc[4][4];
    #pragma unroll
    for (int i = 0; i < 4; ++i)
        #pragma unroll
        for (int j = 0; j < 4; ++j)
            acc[i][j] = f32x4{0.f, 0.f, 0.f, 0.f};

    // ds_read frag base offsets (bytes): row*64, rows = w*64 + f*16 + l15
    int rA[4], rB[4];
    #pragma unroll
    for (int f = 0; f < 4; ++f) {
        rA[f] = (wm*64 + f*16 + l15) * 64;
        rB[f] = (wn*64 + f*16 + l15) * 64;
    }

    // staging geometry: per thread 2 A + 2 B gll16 per K-step
    const int sub  = tid >> 2;     // 0..63 row within 64-row pass
    const int slot = tid & 3;      // 16B slot within 64B row
    const int ldsw = (wid << 10);  // wave-uniform LDS offset within pass

    auto stage = [&](int kt, int bufo) {
        #pragma unroll
        for (int p = 0; p < 2; ++p) {           // A: 2 x 4KB passes
            const int row = p*64 + sub;
            const int gk = (kt << 5) + ((slot ^ (row & 3)) << 3);
            int ar = m0 + row; if (ar > Mc) ar = Mc;
            gll16(A + (size_t)ar * lda + gk, smem + bufo + p*4096 + ldsw);
        }
        #pragma unroll
        for (int p = 0; p < 2; ++p) {           // B: 2 x 4KB passes
            const int row = p*64 + sub;
            const int gk = (kt << 5) + ((slot ^ (row & 3)) << 3);
            gll16(W + (size_t)(n0 + row) * K + gk, smem + bufo + 8192 + p*4096 + ldsw);
        }
    };

    const int nkt = K >> 5;
    stage(0, 0);
    stage(1, 16384);
    asm volatile("s_waitcnt vmcnt(4)" ::: "memory");
    __builtin_amdgcn_s_barrier();

    int curo = 0, nno = 32768;
    for (int t = 0; t < nkt; ++t) {
        const char* cb = smem + curo;
        const int so_ = (lhi ^ sw3) << 4;
        bf16x8 af[4], bg[4];
        #pragma unroll
        for (int f = 0; f < 4; ++f) af[f] = *(const bf16x8*)(cb + rA[f] + so_);
        #pragma unroll
        for (int g = 0; g < 4; ++g) bg[g] = *(const bf16x8*)(cb + 8192 + rB[g] + so_);
        #pragma unroll
        for (int i = 0; i < 4; ++i)
            #pragma unroll
            for (int j = 0; j < 4; ++j)
                acc[i][j] = __builtin_amdgcn_mfma_f32_16x16x32_bf16(
                    af[i], bg[j], acc[i][j], 0, 0, 0);

        if (t + 2 < nkt) {
            stage(t + 2, nno);
            asm volatile("s_waitcnt vmcnt(4)" ::: "memory");   // tile t+1 landed
            __builtin_amdgcn_s_barrier();
        } else if (t + 1 < nkt) {
            asm volatile("s_waitcnt vmcnt(0)" ::: "memory");
            __builtin_amdgcn_s_barrier();
        }
        curo += 16384; if (curo == 49152) curo = 0;
        nno  += 16384; if (nno  == 49152) nno  = 0;
    }

    // ---- epilogue: acc -> swizzled bf16 LDS image [128][128] -> vector IO ----
    __syncthreads();
    #pragma unroll
    for (int i = 0; i < 4; ++i) {
        #pragma unroll
        for (int j = 0; j < 4; ++j) {
            const int colb = (wn*64 + j*16 + l15) * 2;
            const f32x4 v = acc[i][j];
            #pragma unroll
            for (int qq = 0; qq < 4; ++qq) {
                const int row = wm*64 + i*16 + lhi*4 + qq;
                const int ad = row*256 + (colb & 15) + ((((colb >> 4) ^ (row & 7)) & 15) << 4);
                *(bf16*)(smem + ad) = (bf16)v[qq];
            }
        }
    }
    __syncthreads();

    #pragma unroll
    for (int u = 0; u < 8; ++u) {
        const int chunk = u*256 + tid;
        const int rr = chunk >> 4, ss = chunk & 15;
        const int gr = m0 + rr;
        if (gr >= M) continue;
        const int col = n0 + ss*8;
        const bf16x8 v = *(const bf16x8*)(smem + rr*256 + ((ss ^ (rr & 7)) << 4));
        if constexpr (EPI == 0) {
            const size_t ci = coff + (size_t)gr * ldc + col;
            *(bf16x8*)((bf16*)Cbase + ci) = v;
        } else if constexpr (EPI == 1) {
            const float4 b0 = *(const float4*)(bias + col);
            const float4 b1 = *(const float4*)(bias + col + 4);
            bf16x8 o;
            o[0] = (bf16)fmaxf((float)v[0] + b0.x, 0.f);
            o[1] = (bf16)fmaxf((float)v[1] + b0.y, 0.f);
            o[2] = (bf16)fmaxf((float)v[2] + b0.z, 0.f);
            o[3] = (bf16)fmaxf((float)v[3] + b0.w, 0.f);
            o[4] = (bf16)fmaxf((float)v[4] + b1.x, 0.f);
            o[5] = (bf16)fmaxf((float)v[5] + b1.y, 0.f);
            o[6] = (bf16)fmaxf((float)v[6] + b1.z, 0.f);
            o[7] = (bf16)fmaxf((float)v[7] + b1.w, 0.f);
            const size_t ci = coff + (size_t)gr * ldc + col;
            *(bf16x8*)((bf16*)Cbase + ci) = o;
        } else if constexpr (EPI == 2) {
            const bf16x8 uv = *(const bf16x8*)(U + (size_t)gr * ldc + col);
            const float4 d0 = *(const float4*)(dskip + col);
            const float4 d1 = *(const float4*)(dskip + col + 4);
            bf16x8 o;
            o[0] = (bf16)((float)v[0] + d0.x * (float)uv[0]);
            o[1] = (bf16)((float)v[1] + d0.y * (float)uv[1]);
            o[2] = (bf16)((float)v[2] + d0.z * (float)uv[2]);
            o[3] = (bf16)((float)v[3] + d0.w * (float)uv[3]);
            o[4] = (bf16)((float)v[4] + d1.x * (float)uv[4]);
            o[5] = (bf16)((float)v[5] + d1.y * (float)uv[5]);
            o[6] = (bf16)((float)v[6] + d1.z * (float)uv[6]);
            o[7] = (bf16)((float)v[7] + d1.w * (float)uv[7]);
            const size_t ci = coff + (size_t)gr * ldc + col;
            *(bf16x8*)((bf16*)Cbase + ci) = o;
        } else {
            const float4 b0 = *(const float4*)(bias + col);
            const float4 b1 = *(const float4*)(bias + col + 4);
            float xv[8];
            xv[0] = (float)v[0] + b0.x; xv[1] = (float)v[1] + b0.y;
            xv[2] = (float)v[2] + b0.z; xv[3] = (float)v[3] + b0.w;
            xv[4] = (float)v[4] + b1.x; xv[5] = (float)v[5] + b1.y;
            xv[6] = (float)v[6] + b1.z; xv[7] = (float)v[7] + b1.w;
            float4 o0, o1;
            #pragma unroll
            for (int e = 0; e < 8; ++e) {
                const float x = xv[e];
                const float sp = fmaxf(x, 0.f) + log1pf(expf(-fabsf(x)));
                if (e < 4) ((float*)&o0)[e] = sp; else ((float*)&o1)[e-4] = sp;
            }
            const size_t ci = coff + (size_t)gr * ldc + col;
            *(float4*)((float*)Cbase + ci) = o0;
            *(float4*)((float*)Cbase + ci + 4) = o1;
        }
    }
}

// ---------------------------------------------------------------------------
// Chunked LRU scan: T=1000 = 20 chunks x 50.
// ---------------------------------------------------------------------------
__global__ void scan_finals(const bf16* __restrict__ Bu,
                            const float* __restrict__ nu_log,
                            const float* __restrict__ theta_log,
                            float2* __restrict__ finals)
{
    const int g = blockIdx.x * 256 + threadIdx.x;   // 32*20*256
    const int h = g & 255;
    const int c = (g >> 8) % 20;
    const int b = g / 5120;
    const float a  = expf(nu_log[h]);
    const float th = expf(theta_log[h]);
    const float mag = expf(-a);
    const float lre = mag * cosf(th), lim = mag * sinf(th);
    float xre = 0.f, xim = 0.f;
    const bf16* p = Bu + ((size_t)(b*1000 + c*50)) * 512 + h;
    for (int i = 0; i < 50; ++i) {
        const float bre = (float)p[0], bim = (float)p[256];
        const float nre = lre*xre - lim*xim + bre;
        const float nim = lre*xim + lim*xre + bim;
        xre = nre; xim = nim;
        p += 512;
    }
    finals[(b*20 + c)*256 + h] = make_float2(xre, xim);
}

__global__ void scan_carry(const float2* __restrict__ finals,
                           float2* __restrict__ carry,
                           const float* __restrict__ nu_log,
                           const float* __restrict__ theta_log)
{
    const int g = blockIdx.x * 256 + threadIdx.x;   // 32*256
    const int h = g & 255;
    const int b = g >> 8;
    const float a  = expf(nu_log[h]);
    const float th = expf(theta_log[h]);
    const float mag = expf(-50.f * a);
    const float ang = 50.f * th;
    const float cre = mag * cosf(ang), cim = mag * sinf(ang);
    float pre = 0.f, pim = 0.f;
    for (int c = 0; c < 20; ++c) {
        const int idx = (b*20 + c)*256 + h;
        carry[idx] = make_float2(pre, pim);
        const float2 f = finals[idx];
        const float nre = f.x + cre*pre - cim*pim;
        const float nim = f.y + cre*pim + cim*pre;
        pre = nre; pim = nim;
    }
}

__global__ void scan_emit(const bf16* __restrict__ Bu,
                          const float2* __restrict__ carry,
                          const float* __restrict__ nu_log,
                          const float* __restrict__ theta_log,
                          bf16* __restrict__ xs)
{
    const int g = blockIdx.x * 256 + threadIdx.x;
    const int h = g & 255;
    const int c = (g >> 8) % 20;
    const int b = g / 5120;
    const float a  = expf(nu_log[h]);
    const float th = expf(theta_log[h]);
    const float mag = expf(-a);
    const float lre = mag * cosf(th), lim = mag * sinf(th);
    const float2 cr = carry[(b*20 + c)*256 + h];
    float xre = cr.x, xim = cr.y;
    const bf16* p = Bu + ((size_t)(b*1000 + c*50)) * 512 + h;
    bf16* qp = xs + ((size_t)(b*1000 + c*50)) * 512 + h;
    for (int i = 0; i < 50; ++i) {
        const float bre = (float)p[0], bim = (float)p[256];
        const float nre = lre*xre - lim*xim + bre;
        const float nim = lre*xim + lim*xre + bim;
        xre = nre; xim = nim;
        qp[0] = (bf16)xre; qp[256] = (bf16)xim;
        p += 512; qp += 512;
    }
}

// ---------------------------------------------------------------------------
// small kernels
// ---------------------------------------------------------------------------
__global__ void cast8_kern(const float* __restrict__ src, bf16* __restrict__ dst, int n8)
{
    const int i = blockIdx.x * 256 + threadIdx.x;
    if (i >= n8) return;
    const float4* s = (const float4*)src + (size_t)i*2;
    const float4 v0 = s[0], v1 = s[1];
    bf16x8 o;
    o[0] = (bf16)v0.x; o[1] = (bf16)v0.y; o[2] = (bf16)v0.z; o[3] = (bf16)v0.w;
    o[4] = (bf16)v1.x; o[5] = (bf16)v1.y; o[6] = (bf16)v1.z; o[7] = (bf16)v1.w;
    *((bf16x8*)dst + i) = o;
}

__global__ void packWB_kern(const float* __restrict__ Bre, const float* __restrict__ Bim,
                            const float* __restrict__ glog, bf16* __restrict__ WB)
{
    const int idx = blockIdx.x * 256 + threadIdx.x;
    if (idx >= 4*512*768) return;
    const int l = idx / (512*768);
    const int r = idx - l*(512*768);
    const int n = r / 768;
    const int k = r - n*768;
    float v;
    if (n < 256) v = Bre[((size_t)(l*256 + n))*768 + k] * expf(glog[l*256 + n]);
    else         v = Bim[((size_t)(l*256 + (n-256)))*768 + k] * expf(glog[l*256 + (n-256)]);
    WB[idx] = (bf16)v;
}

__global__ void packWC_kern(const float* __restrict__ Cre, const float* __restrict__ Cim,
                            bf16* __restrict__ WC)
{
    const int idx = blockIdx.x * 256 + threadIdx.x;
    if (idx >= 4*768*512) return;
    const int l = idx / (768*512);
    const int r = idx - l*(768*512);
    const int o = r / 512;
    const int k = r - o*512;
    const float v = (k < 256) ? Cre[((size_t)(l*768 + o))*256 + k]
                              : -Cim[((size_t)(l*768 + o))*256 + (k - 256)];
    WC[idx] = (bf16)v;
}

__global__ void ctx_kern(const float* __restrict__ st, const int* __restrict__ sess,
                         const float* __restrict__ cW, const float* __restrict__ cb,
                         float* __restrict__ ctx)
{
    const int b = blockIdx.x;
    const int e = threadIdx.x;
    const int sid = sess[b];
    const float* r = st + (size_t)sid * 64;
    const float* w = cW + (size_t)e * 64;
    float acc = cb[e];
    #pragma unroll 8
    for (int i = 0; i < 64; ++i) acc += r[i] * w[i];
    ctx[b*256 + e] = fmaxf(acc, 0.f);
}

__global__ void ebctx_kern(const float* __restrict__ behav,
                           const float* __restrict__ bW,
                           const float* __restrict__ bB,
                           const int* __restrict__ subj,
                           const float* __restrict__ ctx,
                           bf16* __restrict__ h0)
{
    const int blk = blockIdx.x;          // b*1000 + t
    const int b = blk / 1000;
    const int e = threadIdx.x;
    __shared__ float binp[16];
    if (e < 16) binp[e] = behav[(size_t)blk*16 + e];
    __syncthreads();
    const int s = subj[b];
    const float* w = bW + ((size_t)(s*256) + e)*16;
    float acc = bB[s*256 + e];
    #pragma unroll
    for (int i = 0; i < 16; ++i) acc += binp[i] * w[i];
    acc = fmaxf(acc, 0.f);
    bf16* hp = h0 + (size_t)blk * 768;
    hp[256 + e] = (bf16)acc;
    hp[512 + e] = (bf16)ctx[b*256 + e];
}

__global__ void predb_kern(const bf16* __restrict__ h, const float* __restrict__ W,
                           const float* __restrict__ bb, const int* __restrict__ subj,
                           float* __restrict__ out)
{
    const int lane = threadIdx.x & 63;
    const int wid  = threadIdx.x >> 6;
    const int row  = blockIdx.x * 4 + wid;   // < 32000
    const int b = row / 1000;
    const int s = subj[b];
    const bf16* hr = h + (size_t)row * 768;
    const float* w0 = W + (size_t)(s*2) * 768;
    const float* w1 = w0 + 768;
    float a0 = 0.f, a1 = 0.f;
    #pragma unroll
    for (int j = 0; j < 12; ++j) {
        const int idx = j*64 + lane;
        const float hv = (float)hr[idx];
        a0 += hv * w0[idx];
        a1 += hv * w1[idx];
    }
    #pragma unroll
    for (int m = 32; m >= 1; m >>= 1) {
        a0 += __shfl_xor(a0, m);
        a1 += __shfl_xor(a1, m);
    }
    if (lane == 0) {
        out[(size_t)row*2 + 0] = a0 + bb[s*2 + 0];
        out[(size_t)row*2 + 1] = a1 + bb[s*2 + 1];
    }
}

// ---------------------------------------------------------------------------
extern "C" void kernel_launch(void* const* d_in, const int* in_sizes, int n_in,
                              void* d_out, int out_size, void* d_ws, size_t ws_size,
                              hipStream_t stream)
{
    const float* neural_input   = (const float*)d_in[0];
    const float* behavior_input = (const float*)d_in[1];
    const int*   session_id     = (const int*)d_in[2];
    const int*   subject_id     = (const int*)d_in[3];
    const float* session_table  = (const float*)d_in[4];
    const float* neural_W  = (const float*)d_in[5];
    const float* neural_b  = (const float*)d_in[6];
    const float* behavior_W = (const float*)d_in[7];
    const float* behavior_b = (const float*)d_in[8];
    const float* ctx_W = (const float*)d_in[9];
    const float* ctx_b = (const float*)d_in[10];
    const float* nu_log    = (const float*)d_in[11];
    const float* theta_log = (const float*)d_in[12];
    const float* gamma_log = (const float*)d_in[13];
    const float* B_re = (const float*)d_in[14];
    const float* B_im = (const float*)d_in[15];
    const float* C_re = (const float*)d_in[16];
    const float* C_im = (const float*)d_in[17];
    const float* D_skip = (const float*)d_in[18];
    const float* dec_n_W = (const float*)d_in[19];
    const float* dec_n_b = (const float*)d_in[20];
    const float* dec_b_W = (const float*)d_in[21];
    const float* dec_b_b = (const float*)d_in[22];
    float* out = (float*)d_out;

    char* ws = (char*)d_ws;
    size_t off = 0;
    auto alloc = [&](size_t bytes) -> char* {
        char* p = ws + off;
        off += (bytes + 255) & ~(size_t)255;
        return p;
    };
    bf16*   Wn      = (bf16*)alloc((size_t)8*256*512*2);
    bf16*   Wd      = (bf16*)alloc((size_t)8*512*768*2);
    bf16*   WB      = (bf16*)alloc((size_t)4*512*768*2);
    bf16*   WC      = (bf16*)alloc((size_t)4*768*512*2);
    float*  ctxbuf  = (float*)alloc((size_t)32*256*4);
    bf16*   hA      = (bf16*)alloc((size_t)32*1000*768*2);
    bf16*   hB      = (bf16*)alloc((size_t)32*1000*768*2);
    bf16*   xs      = (bf16*)alloc((size_t)32*1000*512*2);
    float2* finals  = (float2*)alloc((size_t)32*20*256*8);
    float2* carry   = (float2*)alloc((size_t)32*20*256*8);
    bf16*   Bu      = (bf16*)alloc((size_t)32*1000*512*2);
    bf16*   nbf     = Bu;  // alias: neural bf16 consumed before Bu is written

    // --- weight prep / casts ---
    cast8_kern<<<dim3(512),   256, 0, stream>>>(neural_W, Wn, 131072);
    cast8_kern<<<dim3(1536),  256, 0, stream>>>(dec_n_W,  Wd, 393216);
    packWB_kern<<<dim3(6144), 256, 0, stream>>>(B_re, B_im, gamma_log, WB);
    packWC_kern<<<dim3(6144), 256, 0, stream>>>(C_re, C_im, WC);
    ctx_kern<<<dim3(32), 256, 0, stream>>>(session_table, session_id, ctx_W, ctx_b, ctxbuf);
    cast8_kern<<<dim3(8000), 256, 0, stream>>>(neural_input, nbf, 2048000);

    // --- front end: h0 = [relu(en) | relu(eb) | relu(ctx)] ---
    ebctx_kern<<<dim3(32000), 256, 0, stream>>>(behavior_input, behavior_W, behavior_b,
                                                subject_id, ctxbuf, hA);
    // en: M=1000 (z=32), N=256, K=512 -> nbm=8, nbn=2
    gemm_kern<1><<<dim3(16, 1, 32), 256, 0, stream>>>(
        nbf, 512000LL, 512, Wn, 131072LL, neural_b, 256,
        hA, 768000LL, 768, nullptr, nullptr, 0LL, subject_id, 1000, 512, 2);

    // --- 4 LRU layers ---
    for (int l = 0; l < 4; ++l) {
        const bf16* hin  = (l & 1) ? hB : hA;
        bf16*       hout = (l & 1) ? hA : hB;
        // Bu: M=32000, N=512, K=768 -> nbm=250, nbn=4
        gemm_kern<0><<<dim3(1000, 1, 1), 256, 0, stream>>>(
            hin, 0LL, 768, WB + (size_t)l*393216, 0LL, nullptr, 0,
            Bu, 0LL, 512, nullptr, nullptr, 0LL, nullptr, 32000, 768, 4);
        scan_finals<<<dim3(640), 256, 0, stream>>>(Bu, nu_log + l*256, theta_log + l*256, finals);
        scan_carry<<<dim3(32), 256, 0, stream>>>(finals, carry, nu_log + l*256, theta_log + l*256);
        scan_emit<<<dim3(640), 256, 0, stream>>>(Bu, carry, nu_log + l*256, theta_log + l*256, xs);
        // y: M=32000, N=768, K=512 -> nbm=250, nbn=6
        gemm_kern<2><<<dim3(1500, 1, 1), 256, 0, stream>>>(
            xs, 0LL, 512, WC + (size_t)l*393216, 0LL, nullptr, 0,
            hout, 0LL, 768, D_skip + l*768, hin, 0LL, nullptr, 32000, 512, 6);
    }

    // --- decoders (final h is hA after 4 layers) ---
    // dec_n: M=1000 (z=32), N=512, K=768 -> nbm=8, nbn=4
    gemm_kern<3><<<dim3(32, 1, 32), 256, 0, stream>>>(
        hA, 768000LL, 768, Wd, 393216LL, dec_n_b, 512,
        out, 512000LL, 512, nullptr, nullptr, 0LL, subject_id, 1000, 768, 4);
    predb_kern<<<dim3(8000), 256, 0, stream>>>(hA, dec_b_W, dec_b_b, subject_id,
                                               out + 16384000);
}